// Round 8
// baseline (11.754 us; speedup 1.0000x reference)
//
#include <hip/hip_runtime.h>

// CaptionEmbedder: out[b,l,:] = select-by-mask gather of a 512-float row.
//   VOCAB=32000, N_ENT=64, N_FACT=512, D=512, B=128, L=128
//   mask==1 -> entities_encoded[b, clamp(ci - VOCAB, ->N_ENT-1)]
//   mask==2 -> facts_encoded[b, clamp(ci - VOCAB - N_ENT, ->N_FACT-1)]
//   else    -> word_embedding[ci >= VOCAB ? pad : ci]
// R7 best (11.46us): BLOCK=1024, ILP=2, NT stores, 1024 WGs.
// R8: 512 WGs, grid-stride 2 iterations (persistent-ish waves), same ILP=2+NT.

constexpr int VOCAB  = 32000;
constexpr int N_ENT  = 64;
constexpr int N_FACT = 512;
constexpr int D      = 512;
constexpr int L      = 128;

typedef float f32x4 __attribute__((ext_vector_type(4)));

constexpr int TPR   = D / 4;   // 128 threads per row, 1 float4 each
constexpr int BLOCK = 1024;
constexpr int GRID  = 512;     // half the threads -> 2 grid-stride iters
constexpr int ITERS = 2;

__device__ __forceinline__ const f32x4* row_src(
    int ci, int m, int b, int pad,
    const f32x4* __restrict__ ents,
    const f32x4* __restrict__ facts,
    const f32x4* __restrict__ words)
{
    if (m == 1) {
        int e = ci - VOCAB;
        if (e < 0 || e >= N_ENT) e = N_ENT - 1;
        return ents + ((long)b * N_ENT + e) * TPR;
    } else if (m == 2) {
        int f = ci - VOCAB - N_ENT;
        if (f < 0 || f >= N_FACT) f = N_FACT - 1;
        return facts + ((long)b * N_FACT + f) * TPR;
    } else {
        int w = (ci >= VOCAB) ? pad : ci;
        return words + (long)w * TPR;
    }
}

__global__ __launch_bounds__(BLOCK) void caption_embed_kernel(
    const int*   __restrict__ idx,     // [B*L]
    const f32x4* __restrict__ ents,    // [B, N_ENT, D/4]
    const f32x4* __restrict__ facts,   // [B, N_FACT, D/4]
    const f32x4* __restrict__ words,   // [VOCAB, D/4]
    const int*   __restrict__ pad_tok, // [1]
    const int*   __restrict__ masks,   // [B*L]
    f32x4*       __restrict__ out,     // [B*L, D/4]
    int quarter_rows)                  // n_rows / 4 = 4096
{
    const int base = blockIdx.x * BLOCK + threadIdx.x;  // 0 .. 512*1024-1
    const int col  = base % TPR;
    const int pad  = pad_tok[0];

#pragma unroll
    for (int it = 0; it < ITERS; ++it) {
        // iter 0: quarters 0 & 2; iter 1: quarters 1 & 3 — writes stay
        // fully sequential within each quarter.
        const int row0 = base / TPR + it * quarter_rows * 2;
        const int row1 = row0 + quarter_rows;

        const int ci0 = idx[row0];
        const int m0  = masks[row0];
        const int ci1 = idx[row1];
        const int m1  = masks[row1];

        const f32x4* s0 = row_src(ci0, m0, row0 / L, pad, ents, facts, words);
        const f32x4* s1 = row_src(ci1, m1, row1 / L, pad, ents, facts, words);

        f32x4 v0 = s0[col];
        f32x4 v1 = s1[col];

        __builtin_nontemporal_store(v0, &out[(long)row0 * TPR + col]);
        __builtin_nontemporal_store(v1, &out[(long)row1 * TPR + col]);
    }
}

extern "C" void kernel_launch(void* const* d_in, const int* in_sizes, int n_in,
                              void* d_out, int out_size, void* d_ws, size_t ws_size,
                              hipStream_t stream) {
    const int*   idx     = (const int*)d_in[0];
    const f32x4* ents    = (const f32x4*)d_in[1];
    const f32x4* facts   = (const f32x4*)d_in[2];
    const f32x4* words   = (const f32x4*)d_in[3];
    const int*   pad_tok = (const int*)d_in[4];
    const int*   masks   = (const int*)d_in[5];
    f32x4*       out     = (f32x4*)d_out;

    const int n_rows       = in_sizes[0];     // B*L = 16384
    const int quarter_rows = n_rows / 4;      // 4096

    caption_embed_kernel<<<GRID, BLOCK, 0, stream>>>(
        idx, ents, facts, words, pad_tok, masks, out, quarter_rows);
}